// Round 1
// baseline (411.668 us; speedup 1.0000x reference)
//
#include <hip/hip_runtime.h>
#include <hip/hip_bf16.h>

#define NROWS   131072
#define LMD     1024
#define GNND    200
#define HD      128
#define K2PAD   224              // gnn K padded to multiple of 32
#define BLOCK   256
#define WARPS   4
#define ROWS_PER_BLOCK (WARPS*16)
#define NBLK    (NROWS / ROWS_PER_BLOCK)   // 2048

typedef __attribute__((ext_vector_type(4))) float  f32x4;
typedef __attribute__((ext_vector_type(8))) short  bf16x8;

__device__ __forceinline__ short f2bf(float x) {
    union { __hip_bfloat16 h; short s; } u;
    u.h = __float2bfloat16(x);
    return u.s;
}

__device__ __forceinline__ bf16x8 cvt8(f32x4 a, f32x4 b) {
    bf16x8 r;
    r[0]=f2bf(a[0]); r[1]=f2bf(a[1]); r[2]=f2bf(a[2]); r[3]=f2bf(a[3]);
    r[4]=f2bf(b[0]); r[5]=f2bf(b[1]); r[6]=f2bf(b[2]); r[7]=f2bf(b[3]);
    return r;
}

__device__ __forceinline__ float red16(float v) {
    #pragma unroll
    for (int m=1; m<16; m<<=1) v += __shfl_xor(v, m, 16);
    return v;
}

// ---- prep: W1T[h][k] = bf16(lm_W[k][h]) ; W2T[h][k] = bf16(gnn_W[k][h]) zero-padded ----
__global__ void prep_weights(const float* __restrict__ lm_W,
                             const float* __restrict__ gnn_W,
                             short* __restrict__ W1T, short* __restrict__ W2T)
{
    int idx = blockIdx.x*blockDim.x + threadIdx.x;
    if (idx < HD*LMD) {
        int h = idx / LMD, k = idx % LMD;
        W1T[idx] = f2bf(lm_W[(long)k*HD + h]);
    }
    if (idx < HD*K2PAD) {
        int h = idx / K2PAD, k = idx % K2PAD;
        float v = (k < GNND) ? gnn_W[(long)k*HD + h] : 0.0f;
        W2T[idx] = f2bf(v);
    }
}

__device__ __forceinline__ void gnn_gemm(const float* __restrict__ A,
                                         const short*  __restrict__ W2T,
                                         const float* __restrict__ gnn_b,
                                         int col, int g, f32x4 (&acc)[8])
{
    const f32x4 fz = {0.f,0.f,0.f,0.f};
    const bf16x8 bz = {0,0,0,0,0,0,0,0};
    #pragma unroll
    for (int t=0;t<8;t++) acc[t] = fz;
    #pragma unroll
    for (int ks=0; ks<K2PAD/32; ++ks) {
        const int kb = ks*32 + g*8;
        bf16x8 af;
        if (kb < GNND) {
            f32x4 a0 = *(const f32x4*)(A + kb);
            f32x4 a1 = *(const f32x4*)(A + kb + 4);
            af = cvt8(a0, a1);
        } else {
            af = bz;
        }
        #pragma unroll
        for (int t=0;t<8;t++) {
            bf16x8 bf = *(const bf16x8*)(W2T + (t*16+col)*K2PAD + kb);
            acc[t] = __builtin_amdgcn_mfma_f32_16x16x32_bf16(af, bf, acc[t], 0,0,0);
        }
    }
    #pragma unroll
    for (int t=0;t<8;t++) {
        float b = gnn_b[t*16+col];
        #pragma unroll
        for (int r=0;r<4;r++) acc[t][r] += b;
    }
}

__global__ __launch_bounds__(BLOCK) void fused(
    const float* __restrict__ lm,  const float* __restrict__ gnn,
    const float* __restrict__ ngn,
    const float* __restrict__ lm_b, const float* __restrict__ gnn_b,
    const short* __restrict__ W1T,  const short* __restrict__ W2T,
    float* __restrict__ partials)
{
    const int tid  = threadIdx.x;
    const int lane = tid & 63;
    const int win  = tid >> 6;
    const int col  = lane & 15;     // A-row index for loads / D-col in epilogue
    const int g    = lane >> 4;     // k-group
    const long wid = (long)blockIdx.x * WARPS + win;
    const long r0  = wid * 16;
    const long arow = r0 + col;

    const float CC   = 1.0f / 11008.0f;
    const float LOGC = -9.3063777f;   // log(1/11008)
    const f32x4 fz = {0.f,0.f,0.f,0.f};

    f32x4 accL[8], accG[8];
    float pos_acc = 0.f, neg_acc = 0.f;

    // ---- lm GEMM: l = lm[16 rows] @ W1 + b ----
    {
        const float* A = lm + arow * LMD;
        #pragma unroll
        for (int t=0;t<8;t++) accL[t] = fz;
        #pragma unroll 2
        for (int ks=0; ks<LMD/32; ++ks) {
            const int kb = ks*32 + g*8;
            f32x4 a0 = *(const f32x4*)(A + kb);
            f32x4 a1 = *(const f32x4*)(A + kb + 4);
            bf16x8 af = cvt8(a0, a1);
            #pragma unroll
            for (int t=0;t<8;t++) {
                bf16x8 bf = *(const bf16x8*)(W1T + (t*16+col)*LMD + kb);
                accL[t] = __builtin_amdgcn_mfma_f32_16x16x32_bf16(af, bf, accL[t], 0,0,0);
            }
        }
        #pragma unroll
        for (int t=0;t<8;t++) {
            float b = lm_b[t*16+col];
            #pragma unroll
            for (int r=0;r<4;r++) accL[t][r] += b;
        }
    }

    // ---- pos: g-branch GEMM, then per-row normalize + dot ----
    gnn_gemm(gnn + arow * GNND, W2T, gnn_b, col, g, accG);
    #pragma unroll
    for (int r=0;r<4;r++) {
        float lg=0.f, ll=0.f, gg=0.f;
        #pragma unroll
        for (int t=0;t<8;t++) {
            float lv=accL[t][r], gv=accG[t][r];
            lg += lv*gv; ll += lv*lv; gg += gv*gv;
        }
        lg=red16(lg); ll=red16(ll); gg=red16(gg);
        float d  = lg * rsqrtf(ll*gg);
        float pi = d - logf(expf(d)+CC);     // log(ratio)
        if (col==0) pos_acc += pi;
    }

    // ---- neg branch ----
    gnn_gemm(ngn + arow * GNND, W2T, gnn_b, col, g, accG);
    #pragma unroll
    for (int r=0;r<4;r++) {
        float ln=0.f, nn=0.f, ll=0.f;
        #pragma unroll
        for (int t=0;t<8;t++) {
            float lv=accL[t][r], nv=accG[t][r];
            ln += lv*nv; nn += nv*nv; ll += lv*lv;
        }
        ln=red16(ln); nn=red16(nn); ll=red16(ll);
        float d  = ln * rsqrtf(ll*nn);
        float ni = LOGC - logf(expf(d)+CC);  // log(1-ratio)
        if (col==0) neg_acc += ni;
    }

    // ---- wave + block reduce, write per-block partials (deterministic) ----
    #pragma unroll
    for (int m=1;m<64;m<<=1) {
        pos_acc += __shfl_xor(pos_acc, m, 64);
        neg_acc += __shfl_xor(neg_acc, m, 64);
    }
    __shared__ float sp[WARPS], sn[WARPS];
    if (lane==0) { sp[win]=pos_acc; sn[win]=neg_acc; }
    __syncthreads();
    if (tid==0) {
        float p=0.f,n=0.f;
        #pragma unroll
        for (int w=0;w<WARPS;w++){ p+=sp[w]; n+=sn[w]; }
        partials[blockIdx.x*2]   = p;
        partials[blockIdx.x*2+1] = n;
    }
}

__global__ void finalize(const float* __restrict__ partials, float* __restrict__ out)
{
    __shared__ float sp[BLOCK], sn[BLOCK];
    float p=0.f, n=0.f;
    for (int i=threadIdx.x; i<NBLK; i+=BLOCK) { p += partials[2*i]; n += partials[2*i+1]; }
    sp[threadIdx.x]=p; sn[threadIdx.x]=n;
    __syncthreads();
    for (int s=BLOCK/2; s>0; s>>=1) {
        if (threadIdx.x < s) { sp[threadIdx.x]+=sp[threadIdx.x+s]; sn[threadIdx.x]+=sn[threadIdx.x+s]; }
        __syncthreads();
    }
    if (threadIdx.x==0) out[0] = -(sp[0]+sn[0]) / (float)NROWS;
}

extern "C" void kernel_launch(void* const* d_in, const int* in_sizes, int n_in,
                              void* d_out, int out_size, void* d_ws, size_t ws_size,
                              hipStream_t stream)
{
    const float* lm    = (const float*)d_in[0];
    const float* gnn   = (const float*)d_in[1];
    const float* ngn   = (const float*)d_in[2];
    const float* lm_W  = (const float*)d_in[3];
    const float* lm_b  = (const float*)d_in[4];
    const float* gnn_W = (const float*)d_in[5];
    const float* gnn_b = (const float*)d_in[6];

    short* W1T = (short*)d_ws;                                   // 262144 B
    short* W2T = (short*)((char*)d_ws + 262144);                 // 57344 B
    float* partials = (float*)((char*)d_ws + 262144 + 57344);    // 16 KB

    prep_weights<<<512, BLOCK, 0, stream>>>(lm_W, gnn_W, W1T, W2T);
    fused<<<NBLK, BLOCK, 0, stream>>>(lm, gnn, ngn, lm_b, gnn_b, W1T, W2T, partials);
    finalize<<<1, BLOCK, 0, stream>>>(partials, (float*)d_out);
}